// Round 2
// baseline (417.472 us; speedup 1.0000x reference)
//
#include <hip/hip_runtime.h>
#include <hip/hip_bf16.h>

typedef __attribute__((ext_vector_type(8))) short short8;
typedef __attribute__((ext_vector_type(4))) float f32x4;

#define NT 110592   // 48^3 tokens

static __device__ __forceinline__ unsigned int f2bf(float f){
  unsigned int x; __builtin_memcpy(&x,&f,4);
  x += 0x7fffu + ((x>>16)&1u);           // round-to-nearest-even
  return x >> 16;
}

static __device__ __forceinline__ void gll16(const unsigned short* g, unsigned short* l){
  typedef const __attribute__((address_space(1))) unsigned int gu32;
  typedef __attribute__((address_space(3))) unsigned int lu32;
  __builtin_amdgcn_global_load_lds((gu32*)(const void*)g, (lu32*)(void*)l, 16, 0, 0);
}

// ---------- x fp32 -> bf16, 8 elems/thread ----------
__global__ void xconv(const float* __restrict__ x, unsigned short* __restrict__ o){
  size_t i = ((size_t)blockIdx.x*256 + threadIdx.x) * 8;
  float4 a = *(const float4*)(x+i), b = *(const float4*)(x+i+4);
  uint4 pk;
  pk.x = f2bf(a.x)|(f2bf(a.y)<<16); pk.y = f2bf(a.z)|(f2bf(a.w)<<16);
  pk.z = f2bf(b.x)|(f2bf(b.y)<<16); pk.w = f2bf(b.z)|(f2bf(b.w)<<16);
  *(uint4*)(o+i) = pk;
}

// ---------- weight convert+transpose: fp32 [R][C] -> bf16 [C][R] ----------
__global__ void tpose(const float* __restrict__ in, unsigned short* __restrict__ out,
                      int R, int Cc){
  int id = blockIdx.x*256 + threadIdx.x;
  if (id < R*Cc){ int r = id / Cc, c = id - r*Cc; out[c*R + r] = (unsigned short)f2bf(in[id]); }
}

// ---------- small-K MFMA GEMM, B-panel resident in LDS, barrier-free M-loop ----
// K fixed = 256. Per block: stage B panel [128 cols][256] (64 KB) ONCE (1 barrier),
// then grid-stride over SPB 128-row M-strips: A frags straight global->VGPR
// (no A LDS, no K-loop barriers), waves fully independent after the single sync.
// Wave layout 4x1: wave owns 32 rows x 128 cols -> each A elem loaded once.
// B LDS uses the proven XOR col-group swizzle (0 bank conflicts measured):
// elem (row, kf*32 + g*8+e) stored at [row][kf][(g^((row>>1)&3))*8+e];
// frag read group = q ^ ((l16>>1)&3). XCD-bijective block swizzle, bn fastest.
template<bool CF32>
__global__ __launch_bounds__(256) void gemm_bres(
    const unsigned short* __restrict__ A,    // [M][256] bf16
    const unsigned short* __restrict__ Bt,   // [N][256] bf16
    const float* __restrict__ bias,          // [N] fp32 (CF32 only)
    void* __restrict__ Cv,
    int M, int N, int SPB)
{
  __shared__ __align__(16) unsigned short Bs[128*256];   // 64 KB

  // XCD-bijective swizzle (m204): each XCD owns a contiguous swz chunk
  const int nwg = gridDim.x;
  const int bid = blockIdx.x;
  const int qq = nwg >> 3, rr = nwg & 7;
  const int xcd = bid & 7, loc = bid >> 3;
  const int swz = (xcd < rr ? xcd*(qq+1) : rr*(qq+1) + (xcd-rr)*qq) + loc;
  const int nbn = N >> 7;
  const int bn = swz % nbn;           // bn fastest: same-strip blocks share XCD L2
  const int mc = swz / nbn;

  const int tid  = threadIdx.x;
  const int lane = tid & 63;
  const int wave = tid >> 6;
  const int l16 = lane & 15, q = lane >> 4;
  const int cg  = ((q ^ ((l16>>1)&3)) << 3);   // swizzled elem group for B frag reads

  // ---- stage B panel: 16 rounds x 256 threads x 16B = 64 KB ----
  #pragma unroll
  for (int rnd = 0; rnd < 16; ++rnd){
    int u   = rnd*256 + tid;           // 16B slot index
    int row = u >> 5;                  // 32 slots per 256-elem row
    int w   = u & 31;
    int kf  = w >> 2, g = w & 3;
    int col = kf*32 + ((g ^ ((row>>1)&3)) << 3);
    gll16(Bt + (size_t)(bn*128 + row)*256 + col, &Bs[(size_t)u*8]);
  }
  __syncthreads();     // the ONLY barrier

  float bv[8];
  if (CF32){
    #pragma unroll
    for (int tn = 0; tn < 8; ++tn) bv[tn] = bias[bn*128 + tn*16 + l16];
  }

  for (int t = 0; t < SPB; ++t){
    const int strip = mc*SPB + t;
    const unsigned short* Ab = A + (size_t)(strip*128 + wave*32)*256;

    // A fragments: 16 x dwordx4 direct from global (L2/L3-hit), deep MLP
    short8 af[2][8];
    #pragma unroll
    for (int tm = 0; tm < 2; ++tm)
      #pragma unroll
      for (int kf = 0; kf < 8; ++kf)
        af[tm][kf] = *(const short8*)(Ab + (size_t)(tm*16 + l16)*256 + kf*32 + q*8);

    f32x4 acc[2][8] = {};
    #pragma unroll
    for (int kf = 0; kf < 8; ++kf){
      short8 bfm[8];
      #pragma unroll
      for (int tn = 0; tn < 8; ++tn)
        bfm[tn] = *(const short8*)&Bs[(tn*16 + l16)*256 + kf*32 + cg];
      #pragma unroll
      for (int tm = 0; tm < 2; ++tm)
        #pragma unroll
        for (int tn = 0; tn < 8; ++tn)
          acc[tm][tn] = __builtin_amdgcn_mfma_f32_16x16x32_bf16(af[tm][kf], bfm[tn], acc[tm][tn], 0, 0, 0);
    }

    // epilogue (overlaps next strip's loads; no barrier)
    #pragma unroll
    for (int tn = 0; tn < 8; ++tn){
      int col = bn*128 + tn*16 + l16;
      #pragma unroll
      for (int tm = 0; tm < 2; ++tm){
        int row0 = strip*128 + wave*32 + tm*16 + q*4;
        #pragma unroll
        for (int r = 0; r < 4; ++r){
          if (CF32) ((float*)Cv)[(size_t)(row0 + r)*N + col] = acc[tm][tn][r] + bv[tn];
          else ((unsigned short*)Cv)[(size_t)(row0 + r)*N + col] = (unsigned short)f2bf(acc[tm][tn][r]);
        }
      }
    }
  }
}

// ---------- MFMA windowed attention, 1 wave per (window,head), no barriers ----
// S^T = K·Q^T via mfma (rows j, cols i); softmax over j = per-lane sum + 2 shfl;
// P -> LDS (bf16) -> B-frags; V^T staged in LDS; O^T = V^T·P^T via mfma.
// Window map (verified R2): scores window (B,C,A), V/out window (A,B,C),
// masks x|B==11, y|C==11, z|A==11; all coords +2 mod 48 (both rolls folded).
__global__ __launch_bounds__(256) void attn3d(
    const unsigned short* __restrict__ qkv,  // [NT][768] bf16: q|k|v
    unsigned short* __restrict__ aout)       // [NT][256] bf16
{
  __shared__ __align__(16) unsigned short sh[4*6912];   // per wave: P[64][72] + VT[32][72]
  const int tid  = threadIdx.x;
  const int wave = tid >> 6, lane = tid & 63;
  const int l16  = lane & 15, q = lane >> 4;
  unsigned short* P  = sh + wave*6912;
  unsigned short* VT = P + 64*72;

  const int wh   = blockIdx.x*4 + wave;
  const int head = wh & 7;
  const int w    = wh >> 3;
  const int A  = w / 144;
  const int B  = (w / 12) % 12;
  const int Cw = w % 12;

  const int iyy = l16 >> 2, izz = l16 & 3;
  int tok_qk[4], tok_v[4];
  #pragma unroll
  for (int t = 0; t < 4; ++t){
    int px = (4*B  + t   + 2) % 48;
    int py = (4*Cw + iyy + 2) % 48;
    int pz = (4*A  + izz + 2) % 48;
    tok_qk[t] = (px*48 + py)*48 + pz;
    int vx = (4*A  + t   + 2) % 48;
    int vy = (4*B  + iyy + 2) % 48;
    int vz = (4*Cw + izz + 2) % 48;
    tok_v[t] = (vx*48 + vy)*48 + vz;
  }

  // stage V^T: lane = token idx, 32 dims -> scalar b16 writes (2-way free)
  {
    int sx = (4*A  + (lane>>4)     + 2) % 48;
    int sy = (4*B  + ((lane>>2)&3) + 2) % 48;
    int sz = (4*Cw + (lane&3)      + 2) % 48;
    const unsigned short* vp = qkv + (size_t)((sx*48+sy)*48+sz)*768 + 512 + head*32;
    uint4 v0 = *(const uint4*)(vp);
    uint4 v1 = *(const uint4*)(vp+8);
    uint4 v2 = *(const uint4*)(vp+16);
    uint4 v3 = *(const uint4*)(vp+24);
    unsigned vv[16] = {v0.x,v0.y,v0.z,v0.w, v1.x,v1.y,v1.z,v1.w,
                       v2.x,v2.y,v2.z,v2.w, v3.x,v3.y,v3.z,v3.w};
    #pragma unroll
    for (int u = 0; u < 16; ++u){
      VT[(2*u+0)*72 + lane] = (unsigned short)(vv[u] & 0xffffu);
      VT[(2*u+1)*72 + lane] = (unsigned short)(vv[u] >> 16);
    }
  }

  // K/Q fragments straight from global (A/B layout: m|n=l16, k=q*8+j)
  short8 kf[4], qf[4];
  #pragma unroll
  for (int t = 0; t < 4; ++t){
    const unsigned short* base = qkv + (size_t)tok_qk[t]*768 + head*32 + q*8;
    qf[t] = *(const short8*)(base);
    kf[t] = *(const short8*)(base + 256);
  }

  f32x4 s[4][4] = {};
  #pragma unroll
  for (int im = 0; im < 4; ++im)
    #pragma unroll
    for (int jn = 0; jn < 4; ++jn)
      s[im][jn] = __builtin_amdgcn_mfma_f32_16x16x32_bf16(kf[im], qf[jn], s[im][jn], 0, 0, 0);

  // scale + mask + exp (no max-sub: |s|<~8), pack P to LDS, row sums
  const float scale = 0.17677669529663687f;
  const int mx = (B == 11), my = (Cw == 11), mz = (A == 11);
  const int dy = my & ((q>>1) ^ (l16>>3));
  float sum4[4] = {0.f,0.f,0.f,0.f};
  #pragma unroll
  for (int jn = 0; jn < 4; ++jn){
    #pragma unroll
    for (int im = 0; im < 4; ++im){
      const int dxy = (mx & ((im>>1) ^ (jn>>1))) | dy;
      float e0 = (dxy | (mz & (0 ^ ((l16>>1)&1)))) ? 0.f : __expf(s[im][jn][0]*scale);
      float e1 = (dxy | (mz & (0 ^ ((l16>>1)&1)))) ? 0.f : __expf(s[im][jn][1]*scale);
      float e2 = (dxy | (mz & (1 ^ ((l16>>1)&1)))) ? 0.f : __expf(s[im][jn][2]*scale);
      float e3 = (dxy | (mz & (1 ^ ((l16>>1)&1)))) ? 0.f : __expf(s[im][jn][3]*scale);
      sum4[jn] += (e0+e1)+(e2+e3);
      uint2 pk;
      pk.x = f2bf(e0) | (f2bf(e1)<<16);
      pk.y = f2bf(e2) | (f2bf(e3)<<16);
      *(uint2*)&P[(jn*16+l16)*72 + im*16 + q*4] = pk;   // row i, cols j..j+3
    }
  }
  #pragma unroll
  for (int jn = 0; jn < 4; ++jn){
    float sj = sum4[jn];
    sj += __shfl_xor(sj, 16);
    sj += __shfl_xor(sj, 32);
    sum4[jn] = 1.f / sj;
  }

  // O^T = V^T · P^T  (M=32 d, N=64 i, K=64 j)
  f32x4 o[2][4] = {};
  #pragma unroll
  for (int ks = 0; ks < 2; ++ks){
    short8 vf[2], pf[4];
    #pragma unroll
    for (int dt = 0; dt < 2; ++dt)
      vf[dt] = *(const short8*)&VT[(dt*16 + l16)*72 + ks*32 + q*8];
    #pragma unroll
    for (int it = 0; it < 4; ++it)
      pf[it] = *(const short8*)&P[(it*16 + l16)*72 + ks*32 + q*8];
    #pragma unroll
    for (int dt = 0; dt < 2; ++dt)
      #pragma unroll
      for (int it = 0; it < 4; ++it)
        o[dt][it] = __builtin_amdgcn_mfma_f32_16x16x32_bf16(vf[dt], pf[it], o[dt][it], 0, 0, 0);
  }

  // epilogue: O^T[d=dt*16+q*4+r][i=it*16+l16] * inv[it] -> aout[tok_v(i)]
  #pragma unroll
  for (int it = 0; it < 4; ++it){
    float inv = sum4[it];
    unsigned short* op = aout + (size_t)tok_v[it]*256 + head*32;
    #pragma unroll
    for (int dt = 0; dt < 2; ++dt){
      uint2 pk;
      pk.x = f2bf(o[dt][it][0]*inv) | (f2bf(o[dt][it][1]*inv) << 16);
      pk.y = f2bf(o[dt][it][2]*inv) | (f2bf(o[dt][it][3]*inv) << 16);
      *(uint2*)(op + dt*16 + q*4) = pk;
    }
  }
}

// ------------------------------- launch ---------------------------------------
extern "C" void kernel_launch(void* const* d_in, const int* in_sizes, int n_in,
                              void* d_out, int out_size, void* d_ws, size_t ws_size,
                              hipStream_t stream) {
  const float* x     = (const float*)d_in[0];  // [NT][256] fp32
  const float* w_qkv = (const float*)d_in[1];  // [256][768] fp32
  const float* w_out = (const float*)d_in[2];  // [256][256] fp32
  const float* b_out = (const float*)d_in[3];  // [256] fp32
  float* out = (float*)d_out;                  // [NT][256] fp32

  unsigned short* qkv   = (unsigned short*)d_ws;                 // NT*768 bf16
  unsigned short* xbf   = qkv   + (size_t)NT*768;                // NT*256 bf16 (aliases aout)
  unsigned short* aout  = xbf;                                   // reused after GEMM1
  unsigned short* wqkvT = xbf   + (size_t)NT*256;                // 768*256 bf16
  unsigned short* woutT = wqkvT + (size_t)768*256;               // 256*256 bf16
  // total ws use ≈ 227 MB

  xconv<<<dim3(NT*256/2048), dim3(256), 0, stream>>>(x, xbf);
  tpose<<<dim3((256*768 + 255)/256), dim3(256), 0, stream>>>(w_qkv, wqkvT, 256, 768);
  tpose<<<dim3((256*256 + 255)/256), dim3(256), 0, stream>>>(w_out, woutT, 256, 256);

  // M-strips = 864; SPB=2 -> 432 m-chunks. grid = mchunks * nbn (bn fastest in swz)
  gemm_bres<false><<<dim3(432*6), dim3(256), 0, stream>>>(xbf, wqkvT, nullptr, qkv, NT, 768, 2);

  attn3d<<<dim3(13824/4), dim3(256), 0, stream>>>(qkv, aout);

  gemm_bres<true><<<dim3(432*2), dim3(256), 0, stream>>>(aout, woutT, b_out, out, NT, 256, 2);
}

// Round 3
// 368.144 us; speedup vs baseline: 1.1340x; 1.1340x over previous
//
#include <hip/hip_runtime.h>
#include <hip/hip_bf16.h>

typedef __attribute__((ext_vector_type(8))) short short8;
typedef __attribute__((ext_vector_type(4))) float f32x4;

#define NT 110592   // 48^3 tokens

static __device__ __forceinline__ unsigned int f2bf(float f){
  unsigned int x; __builtin_memcpy(&x,&f,4);
  x += 0x7fffu + ((x>>16)&1u);           // round-to-nearest-even
  return x >> 16;
}

static __device__ __forceinline__ void gll16(const unsigned short* g, unsigned short* l){
  typedef const __attribute__((address_space(1))) unsigned int gu32;
  typedef __attribute__((address_space(3))) unsigned int lu32;
  __builtin_amdgcn_global_load_lds((gu32*)(const void*)g, (lu32*)(void*)l, 16, 0, 0);
}

// ---------- x fp32 -> bf16, 8 elems/thread ----------
__global__ void xconv(const float* __restrict__ x, unsigned short* __restrict__ o){
  size_t i = ((size_t)blockIdx.x*256 + threadIdx.x) * 8;
  float4 a = *(const float4*)(x+i), b = *(const float4*)(x+i+4);
  uint4 pk;
  pk.x = f2bf(a.x)|(f2bf(a.y)<<16); pk.y = f2bf(a.z)|(f2bf(a.w)<<16);
  pk.z = f2bf(b.x)|(f2bf(b.y)<<16); pk.w = f2bf(b.z)|(f2bf(b.w)<<16);
  *(uint4*)(o+i) = pk;
}

// ---------- weight convert+transpose: fp32 [R][C] -> bf16 [C][R] ----------
__global__ void tpose(const float* __restrict__ in, unsigned short* __restrict__ out,
                      int R, int Cc){
  int id = blockIdx.x*256 + threadIdx.x;
  if (id < R*Cc){ int r = id / Cc, c = id - r*Cc; out[c*R + r] = (unsigned short)f2bf(in[id]); }
}

// ---------- MFMA GEMM: C[M][N] = A[M][K]*Bt[N][K]^T (+bias), bf16 in ----------
// 128x128 tile, BK=64 (two 32-halves), global_load_lds w16, XOR-swizzled LDS
// (R1-verified: 0 bank conflicts). R3: double-buffered LDS + 2-phase pipeline:
// issue stage(t+1) into buf^1 BEFORE compute(t) on buf; ONE barrier per K-step
// (4+1 total vs 8 full drains in R1). Pre-barrier drain overlaps with the
// ~350cy ds_read+MFMA issue window. buf^1's prior readers passed the previous
// barrier, so the overwrite is race-free.
// 1D grid, XCD-bijective swizzle (m204), bn fastest within XCD chunk.
template<bool CF32>
__global__ __launch_bounds__(256) void gemm_bt(
    const unsigned short* __restrict__ A,    // [M][K] bf16
    const unsigned short* __restrict__ Bt,   // [N][K] bf16
    const float* __restrict__ bias,          // [N] fp32 (CF32 only)
    void* __restrict__ Cv,
    int M, int N, int K)
{
  __shared__ __align__(16) unsigned short As[2*8192];  // 2 bufs x (two 32-wide halves)
  __shared__ __align__(16) unsigned short Bs[2*8192];

  // --- XCD-bijective swizzle: consecutive swz land on same XCD ---
  const int nwg = gridDim.x;
  const int bid = blockIdx.x;
  const int qq = nwg >> 3, rr = nwg & 7;
  const int xcd = bid & 7, loc = bid >> 3;
  const int swz = (xcd < rr ? xcd*(qq+1) : rr*(qq+1) + (xcd-rr)*qq) + loc;
  const int nbn = N >> 7;
  const int bn = swz % nbn;           // bn fastest: A-strip L2/L3 reuse
  const int bm = swz / nbn;

  const int tid  = threadIdx.x;
  const int lane = tid & 63;
  const int wave = tid >> 6;
  const int wm = wave >> 1, wn = wave & 1;
  const int l16 = lane & 15, q = lane >> 4;

  const size_t arow0 = (size_t)(bm*128 + (tid>>2))*K;
  const size_t brow0 = (size_t)(bn*128 + (tid>>2))*K;
  const int g8  = ((tid&3) ^ ((tid>>3)&3)) * 8;   // swizzled memory col for staging
  const int cg8 = (q ^ ((l16>>1)&3)) * 8;         // swizzled LDS col for frag reads

  f32x4 acc[4][4] = {};

  // stage one BK=64 slab into buffer `cur`
  auto stage = [&](int k0, int cur){
    unsigned short* Ad = &As[cur*8192];
    unsigned short* Bd = &Bs[cur*8192];
    gll16(A  + arow0 + k0 + g8,                      &Ad[tid*8]);
    gll16(A  + arow0 + (size_t)64*K + k0 + g8,       &Ad[(tid+256)*8]);
    gll16(A  + arow0 + k0 + 32 + g8,                 &Ad[4096 + tid*8]);
    gll16(A  + arow0 + (size_t)64*K + k0 + 32 + g8,  &Ad[4096 + (tid+256)*8]);
    gll16(Bt + brow0 + k0 + g8,                      &Bd[tid*8]);
    gll16(Bt + brow0 + (size_t)64*K + k0 + g8,       &Bd[(tid+256)*8]);
    gll16(Bt + brow0 + k0 + 32 + g8,                 &Bd[4096 + (tid)*8]);
    gll16(Bt + brow0 + (size_t)64*K + k0 + 32 + g8,  &Bd[4096 + (tid+256)*8]);
  };

  stage(0, 0);
  __syncthreads();

  int cur = 0;
  for (int k0 = 0; k0 < K; k0 += 64){
    if (k0 + 64 < K) stage(k0 + 64, cur ^ 1);   // prefetch next slab (overlaps compute)

    #pragma unroll
    for (int h = 0; h < 2; ++h){
      short8 af[4], bfm[4];
      #pragma unroll
      for (int t = 0; t < 4; ++t){
        af[t]  = *(const short8*)&As[cur*8192 + h*4096 + (wm*64 + t*16 + l16)*32 + cg8];
        bfm[t] = *(const short8*)&Bs[cur*8192 + h*4096 + (wn*64 + t*16 + l16)*32 + cg8];
      }
      #pragma unroll
      for (int im = 0; im < 4; ++im)
        #pragma unroll
        for (int in = 0; in < 4; ++in)
          acc[im][in] = __builtin_amdgcn_mfma_f32_16x16x32_bf16(af[im], bfm[in], acc[im][in], 0, 0, 0);
    }

    if (k0 + 64 < K) __syncthreads();   // drains the (mostly-complete) prefetch
    cur ^= 1;
  }

  #pragma unroll
  for (int in = 0; in < 4; ++in){
    int col = bn*128 + wn*64 + in*16 + l16;
    float bv = CF32 ? bias[col] : 0.f;
    #pragma unroll
    for (int im = 0; im < 4; ++im){
      int row0 = bm*128 + wm*64 + im*16 + q*4;
      #pragma unroll
      for (int r = 0; r < 4; ++r){
        if (CF32) ((float*)Cv)[(size_t)(row0 + r)*N + col] = acc[im][in][r] + bv;
        else ((unsigned short*)Cv)[(size_t)(row0 + r)*N + col] = (unsigned short)f2bf(acc[im][in][r]);
      }
    }
  }
}

// ---------- MFMA windowed attention, 1 wave per (window,head), no barriers ----
// S^T = K·Q^T via mfma (rows j, cols i); softmax over j = per-lane sum + 2 shfl;
// P -> LDS (bf16) -> B-frags; V^T staged in LDS; O^T = V^T·P^T via mfma.
// Window map (verified R2): scores window (B,C,A), V/out window (A,B,C),
// masks x|B==11, y|C==11, z|A==11; all coords +2 mod 48 (both rolls folded).
__global__ __launch_bounds__(256) void attn3d(
    const unsigned short* __restrict__ qkv,  // [NT][768] bf16: q|k|v
    unsigned short* __restrict__ aout)       // [NT][256] bf16
{
  __shared__ __align__(16) unsigned short sh[4*6912];   // per wave: P[64][72] + VT[32][72]
  const int tid  = threadIdx.x;
  const int wave = tid >> 6, lane = tid & 63;
  const int l16  = lane & 15, q = lane >> 4;
  unsigned short* P  = sh + wave*6912;
  unsigned short* VT = P + 64*72;

  const int wh   = blockIdx.x*4 + wave;
  const int head = wh & 7;
  const int w    = wh >> 3;
  const int A  = w / 144;
  const int B  = (w / 12) % 12;
  const int Cw = w % 12;

  const int iyy = l16 >> 2, izz = l16 & 3;
  int tok_qk[4], tok_v[4];
  #pragma unroll
  for (int t = 0; t < 4; ++t){
    int px = (4*B  + t   + 2) % 48;
    int py = (4*Cw + iyy + 2) % 48;
    int pz = (4*A  + izz + 2) % 48;
    tok_qk[t] = (px*48 + py)*48 + pz;
    int vx = (4*A  + t   + 2) % 48;
    int vy = (4*B  + iyy + 2) % 48;
    int vz = (4*Cw + izz + 2) % 48;
    tok_v[t] = (vx*48 + vy)*48 + vz;
  }

  // stage V^T: lane = token idx, 32 dims -> scalar b16 writes (2-way free)
  {
    int sx = (4*A  + (lane>>4)     + 2) % 48;
    int sy = (4*B  + ((lane>>2)&3) + 2) % 48;
    int sz = (4*Cw + (lane&3)      + 2) % 48;
    const unsigned short* vp = qkv + (size_t)((sx*48+sy)*48+sz)*768 + 512 + head*32;
    uint4 v0 = *(const uint4*)(vp);
    uint4 v1 = *(const uint4*)(vp+8);
    uint4 v2 = *(const uint4*)(vp+16);
    uint4 v3 = *(const uint4*)(vp+24);
    unsigned vv[16] = {v0.x,v0.y,v0.z,v0.w, v1.x,v1.y,v1.z,v1.w,
                       v2.x,v2.y,v2.z,v2.w, v3.x,v3.y,v3.z,v3.w};
    #pragma unroll
    for (int u = 0; u < 16; ++u){
      VT[(2*u+0)*72 + lane] = (unsigned short)(vv[u] & 0xffffu);
      VT[(2*u+1)*72 + lane] = (unsigned short)(vv[u] >> 16);
    }
  }

  // K/Q fragments straight from global (A/B layout: m|n=l16, k=q*8+j)
  short8 kf[4], qf[4];
  #pragma unroll
  for (int t = 0; t < 4; ++t){
    const unsigned short* base = qkv + (size_t)tok_qk[t]*768 + head*32 + q*8;
    qf[t] = *(const short8*)(base);
    kf[t] = *(const short8*)(base + 256);
  }

  f32x4 s[4][4] = {};
  #pragma unroll
  for (int im = 0; im < 4; ++im)
    #pragma unroll
    for (int jn = 0; jn < 4; ++jn)
      s[im][jn] = __builtin_amdgcn_mfma_f32_16x16x32_bf16(kf[im], qf[jn], s[im][jn], 0, 0, 0);

  // scale + mask + exp (no max-sub: |s|<~8), pack P to LDS, row sums
  const float scale = 0.17677669529663687f;
  const int mx = (B == 11), my = (Cw == 11), mz = (A == 11);
  const int dy = my & ((q>>1) ^ (l16>>3));
  float sum4[4] = {0.f,0.f,0.f,0.f};
  #pragma unroll
  for (int jn = 0; jn < 4; ++jn){
    #pragma unroll
    for (int im = 0; im < 4; ++im){
      const int dxy = (mx & ((im>>1) ^ (jn>>1))) | dy;
      float e0 = (dxy | (mz & (0 ^ ((l16>>1)&1)))) ? 0.f : __expf(s[im][jn][0]*scale);
      float e1 = (dxy | (mz & (0 ^ ((l16>>1)&1)))) ? 0.f : __expf(s[im][jn][1]*scale);
      float e2 = (dxy | (mz & (1 ^ ((l16>>1)&1)))) ? 0.f : __expf(s[im][jn][2]*scale);
      float e3 = (dxy | (mz & (1 ^ ((l16>>1)&1)))) ? 0.f : __expf(s[im][jn][3]*scale);
      sum4[jn] += (e0+e1)+(e2+e3);
      uint2 pk;
      pk.x = f2bf(e0) | (f2bf(e1)<<16);
      pk.y = f2bf(e2) | (f2bf(e3)<<16);
      *(uint2*)&P[(jn*16+l16)*72 + im*16 + q*4] = pk;   // row i, cols j..j+3
    }
  }
  #pragma unroll
  for (int jn = 0; jn < 4; ++jn){
    float sj = sum4[jn];
    sj += __shfl_xor(sj, 16);
    sj += __shfl_xor(sj, 32);
    sum4[jn] = 1.f / sj;
  }

  // O^T = V^T · P^T  (M=32 d, N=64 i, K=64 j)
  f32x4 o[2][4] = {};
  #pragma unroll
  for (int ks = 0; ks < 2; ++ks){
    short8 vf[2], pf[4];
    #pragma unroll
    for (int dt = 0; dt < 2; ++dt)
      vf[dt] = *(const short8*)&VT[(dt*16 + l16)*72 + ks*32 + q*8];
    #pragma unroll
    for (int it = 0; it < 4; ++it)
      pf[it] = *(const short8*)&P[(it*16 + l16)*72 + ks*32 + q*8];
    #pragma unroll
    for (int dt = 0; dt < 2; ++dt)
      #pragma unroll
      for (int it = 0; it < 4; ++it)
        o[dt][it] = __builtin_amdgcn_mfma_f32_16x16x32_bf16(vf[dt], pf[it], o[dt][it], 0, 0, 0);
  }

  // epilogue: O^T[d=dt*16+q*4+r][i=it*16+l16] * inv[it] -> aout[tok_v(i)]
  #pragma unroll
  for (int it = 0; it < 4; ++it){
    float inv = sum4[it];
    unsigned short* op = aout + (size_t)tok_v[it]*256 + head*32;
    #pragma unroll
    for (int dt = 0; dt < 2; ++dt){
      uint2 pk;
      pk.x = f2bf(o[dt][it][0]*inv) | (f2bf(o[dt][it][1]*inv) << 16);
      pk.y = f2bf(o[dt][it][2]*inv) | (f2bf(o[dt][it][3]*inv) << 16);
      *(uint2*)(op + dt*16 + q*4) = pk;
    }
  }
}

// ------------------------------- launch ---------------------------------------
extern "C" void kernel_launch(void* const* d_in, const int* in_sizes, int n_in,
                              void* d_out, int out_size, void* d_ws, size_t ws_size,
                              hipStream_t stream) {
  const float* x     = (const float*)d_in[0];  // [NT][256] fp32
  const float* w_qkv = (const float*)d_in[1];  // [256][768] fp32
  const float* w_out = (const float*)d_in[2];  // [256][256] fp32
  const float* b_out = (const float*)d_in[3];  // [256] fp32
  float* out = (float*)d_out;                  // [NT][256] fp32

  unsigned short* qkv   = (unsigned short*)d_ws;                 // NT*768 bf16
  unsigned short* xbf   = qkv   + (size_t)NT*768;                // NT*256 bf16 (aliases aout)
  unsigned short* aout  = xbf;                                   // reused after GEMM1
  unsigned short* wqkvT = xbf   + (size_t)NT*256;                // 768*256 bf16
  unsigned short* woutT = wqkvT + (size_t)768*256;               // 256*256 bf16
  // total ws use ≈ 227 MB

  xconv<<<dim3(NT*256/2048), dim3(256), 0, stream>>>(x, xbf);
  tpose<<<dim3((256*768 + 255)/256), dim3(256), 0, stream>>>(w_qkv, wqkvT, 256, 768);
  tpose<<<dim3((256*256 + 255)/256), dim3(256), 0, stream>>>(w_out, woutT, 256, 256);

  // 1D grid + in-kernel XCD-bijective swizzle: A-strip fetched once per XCD
  gemm_bt<false><<<dim3((768/128)*(NT/128)), dim3(256), 0, stream>>>(xbf, wqkvT, nullptr, qkv, NT, 768, 256);

  attn3d<<<dim3(13824/4), dim3(256), 0, stream>>>(qkv, aout);

  gemm_bt<true><<<dim3((256/128)*(NT/128)), dim3(256), 0, stream>>>(aout, woutT, b_out, out, NT, 256, 256);
}

// Round 4
// 359.063 us; speedup vs baseline: 1.1627x; 1.0253x over previous
//
#include <hip/hip_runtime.h>
#include <hip/hip_bf16.h>

typedef __attribute__((ext_vector_type(8))) short short8;
typedef __attribute__((ext_vector_type(4))) float f32x4;

#define NT 110592   // 48^3 tokens

static __device__ __forceinline__ unsigned int f2bf(float f){
  unsigned int x; __builtin_memcpy(&x,&f,4);
  x += 0x7fffu + ((x>>16)&1u);           // round-to-nearest-even
  return x >> 16;
}

static __device__ __forceinline__ void gll16(const unsigned short* g, unsigned short* l){
  typedef const __attribute__((address_space(1))) unsigned int gu32;
  typedef __attribute__((address_space(3))) unsigned int lu32;
  __builtin_amdgcn_global_load_lds((gu32*)(const void*)g, (lu32*)(void*)l, 16, 0, 0);
}

// ---------- x fp32 -> bf16, 8 elems/thread ----------
__global__ void xconv(const float* __restrict__ x, unsigned short* __restrict__ o){
  size_t i = ((size_t)blockIdx.x*256 + threadIdx.x) * 8;
  float4 a = *(const float4*)(x+i), b = *(const float4*)(x+i+4);
  uint4 pk;
  pk.x = f2bf(a.x)|(f2bf(a.y)<<16); pk.y = f2bf(a.z)|(f2bf(a.w)<<16);
  pk.z = f2bf(b.x)|(f2bf(b.y)<<16); pk.w = f2bf(b.z)|(f2bf(b.w)<<16);
  *(uint4*)(o+i) = pk;
}

// ---------- weight convert+transpose: fp32 [R][C] -> bf16 [C][R] ----------
__global__ void tpose(const float* __restrict__ in, unsigned short* __restrict__ out,
                      int R, int Cc){
  int id = blockIdx.x*256 + threadIdx.x;
  if (id < R*Cc){ int r = id / Cc, c = id - r*Cc; out[c*R + r] = (unsigned short)f2bf(in[id]); }
}

// ---------- MFMA GEMM: C[M][N] = A[M][K]*Bt[N][K]^T (+bias), bf16 in ----------
// 128x128 tile, BK=64 (two 32-halves), global_load_lds w16, XOR-swizzled LDS
// (verified 0 bank conflicts). R4: 512-thread blocks, 8 waves (4x2), per-wave
// 32x64 tile, acc[2][4] = 32 VGPR; __launch_bounds__(512,8) targets VGPR<=64
// -> 8 waves/SIMD = 32 waves/CU (2x R1's occupancy). LDS layout/swizzle and
// staging pattern identical to R1 (single-buffer, 2 barriers/K-step); only the
// thread->work map changes: 512 threads cover rows 0..127 in one gll16 pass.
// 1D grid, XCD-bijective swizzle (m204), bn fastest within XCD chunk.
template<bool CF32>
__global__ __launch_bounds__(512, 8) void gemm_bt(
    const unsigned short* __restrict__ A,    // [M][K] bf16
    const unsigned short* __restrict__ Bt,   // [N][K] bf16
    const float* __restrict__ bias,          // [N] fp32 (CF32 only)
    void* __restrict__ Cv,
    int M, int N, int K)
{
  __shared__ __align__(16) unsigned short As[2*4096];  // two 32-wide halves, 16 KB
  __shared__ __align__(16) unsigned short Bs[2*4096];

  // --- XCD-bijective swizzle: consecutive swz land on same XCD ---
  const int nwg = gridDim.x;
  const int bid = blockIdx.x;
  const int qq = nwg >> 3, rr = nwg & 7;
  const int xcd = bid & 7, loc = bid >> 3;
  const int swz = (xcd < rr ? xcd*(qq+1) : rr*(qq+1) + (xcd-rr)*qq) + loc;
  const int nbn = N >> 7;
  const int bn = swz % nbn;           // bn fastest: A-strip L2/L3 reuse
  const int bm = swz / nbn;

  const int tid  = threadIdx.x;       // 0..511
  const int lane = tid & 63;
  const int wave = tid >> 6;          // 0..7
  const int wm = wave >> 1, wn = wave & 1;   // 4x2 wave grid: 32 rows x 64 cols
  const int l16 = lane & 15, q = lane >> 4;

  const size_t arow0 = (size_t)(bm*128 + (tid>>2))*K;   // rows 0..127
  const size_t brow0 = (size_t)(bn*128 + (tid>>2))*K;
  const int g8  = ((tid&3) ^ ((tid>>3)&3)) * 8;   // swizzled memory col for staging
  const int cg8 = (q ^ ((l16>>1)&3)) * 8;         // swizzled LDS col for frag reads

  f32x4 acc[2][4] = {};

  for (int k0 = 0; k0 < K; k0 += 64){
    __syncthreads();
    gll16(A  + arow0 + k0 + g8,       &As[tid*8]);          // half0 (cols k0..k0+31)
    gll16(A  + arow0 + k0 + 32 + g8,  &As[4096 + tid*8]);   // half1
    gll16(Bt + brow0 + k0 + g8,       &Bs[tid*8]);
    gll16(Bt + brow0 + k0 + 32 + g8,  &Bs[4096 + tid*8]);
    __syncthreads();

    #pragma unroll
    for (int h = 0; h < 2; ++h){
      short8 af[2], bfm[4];
      #pragma unroll
      for (int t = 0; t < 2; ++t)
        af[t]  = *(const short8*)&As[h*4096 + (wm*32 + t*16 + l16)*32 + cg8];
      #pragma unroll
      for (int t = 0; t < 4; ++t)
        bfm[t] = *(const short8*)&Bs[h*4096 + (wn*64 + t*16 + l16)*32 + cg8];
      #pragma unroll
      for (int im = 0; im < 2; ++im)
        #pragma unroll
        for (int in = 0; in < 4; ++in)
          acc[im][in] = __builtin_amdgcn_mfma_f32_16x16x32_bf16(af[im], bfm[in], acc[im][in], 0, 0, 0);
    }
  }

  #pragma unroll
  for (int in = 0; in < 4; ++in){
    int col = bn*128 + wn*64 + in*16 + l16;
    float bv = CF32 ? bias[col] : 0.f;
    #pragma unroll
    for (int im = 0; im < 2; ++im){
      int row0 = bm*128 + wm*32 + im*16 + q*4;
      #pragma unroll
      for (int r = 0; r < 4; ++r){
        if (CF32) ((float*)Cv)[(size_t)(row0 + r)*N + col] = acc[im][in][r] + bv;
        else ((unsigned short*)Cv)[(size_t)(row0 + r)*N + col] = (unsigned short)f2bf(acc[im][in][r]);
      }
    }
  }
}

// ---------- MFMA windowed attention, 1 wave per (window,head), no barriers ----
// S^T = K·Q^T via mfma (rows j, cols i); softmax over j = per-lane sum + 2 shfl;
// P -> LDS (bf16) -> B-frags; V^T staged in LDS; O^T = V^T·P^T via mfma.
// Window map (verified R2): scores window (B,C,A), V/out window (A,B,C),
// masks x|B==11, y|C==11, z|A==11; all coords +2 mod 48 (both rolls folded).
__global__ __launch_bounds__(256) void attn3d(
    const unsigned short* __restrict__ qkv,  // [NT][768] bf16: q|k|v
    unsigned short* __restrict__ aout)       // [NT][256] bf16
{
  __shared__ __align__(16) unsigned short sh[4*6912];   // per wave: P[64][72] + VT[32][72]
  const int tid  = threadIdx.x;
  const int wave = tid >> 6, lane = tid & 63;
  const int l16  = lane & 15, q = lane >> 4;
  unsigned short* P  = sh + wave*6912;
  unsigned short* VT = P + 64*72;

  const int wh   = blockIdx.x*4 + wave;
  const int head = wh & 7;
  const int w    = wh >> 3;
  const int A  = w / 144;
  const int B  = (w / 12) % 12;
  const int Cw = w % 12;

  const int iyy = l16 >> 2, izz = l16 & 3;
  int tok_qk[4], tok_v[4];
  #pragma unroll
  for (int t = 0; t < 4; ++t){
    int px = (4*B  + t   + 2) % 48;
    int py = (4*Cw + iyy + 2) % 48;
    int pz = (4*A  + izz + 2) % 48;
    tok_qk[t] = (px*48 + py)*48 + pz;
    int vx = (4*A  + t   + 2) % 48;
    int vy = (4*B  + iyy + 2) % 48;
    int vz = (4*Cw + izz + 2) % 48;
    tok_v[t] = (vx*48 + vy)*48 + vz;
  }

  // stage V^T: lane = token idx, 32 dims -> scalar b16 writes (2-way free)
  {
    int sx = (4*A  + (lane>>4)     + 2) % 48;
    int sy = (4*B  + ((lane>>2)&3) + 2) % 48;
    int sz = (4*Cw + (lane&3)      + 2) % 48;
    const unsigned short* vp = qkv + (size_t)((sx*48+sy)*48+sz)*768 + 512 + head*32;
    uint4 v0 = *(const uint4*)(vp);
    uint4 v1 = *(const uint4*)(vp+8);
    uint4 v2 = *(const uint4*)(vp+16);
    uint4 v3 = *(const uint4*)(vp+24);
    unsigned vv[16] = {v0.x,v0.y,v0.z,v0.w, v1.x,v1.y,v1.z,v1.w,
                       v2.x,v2.y,v2.z,v2.w, v3.x,v3.y,v3.z,v3.w};
    #pragma unroll
    for (int u = 0; u < 16; ++u){
      VT[(2*u+0)*72 + lane] = (unsigned short)(vv[u] & 0xffffu);
      VT[(2*u+1)*72 + lane] = (unsigned short)(vv[u] >> 16);
    }
  }

  // K/Q fragments straight from global (A/B layout: m|n=l16, k=q*8+j)
  short8 kf[4], qf[4];
  #pragma unroll
  for (int t = 0; t < 4; ++t){
    const unsigned short* base = qkv + (size_t)tok_qk[t]*768 + head*32 + q*8;
    qf[t] = *(const short8*)(base);
    kf[t] = *(const short8*)(base + 256);
  }

  f32x4 s[4][4] = {};
  #pragma unroll
  for (int im = 0; im < 4; ++im)
    #pragma unroll
    for (int jn = 0; jn < 4; ++jn)
      s[im][jn] = __builtin_amdgcn_mfma_f32_16x16x32_bf16(kf[im], qf[jn], s[im][jn], 0, 0, 0);

  // scale + mask + exp (no max-sub: |s|<~8), pack P to LDS, row sums
  const float scale = 0.17677669529663687f;
  const int mx = (B == 11), my = (Cw == 11), mz = (A == 11);
  const int dy = my & ((q>>1) ^ (l16>>3));
  float sum4[4] = {0.f,0.f,0.f,0.f};
  #pragma unroll
  for (int jn = 0; jn < 4; ++jn){
    #pragma unroll
    for (int im = 0; im < 4; ++im){
      const int dxy = (mx & ((im>>1) ^ (jn>>1))) | dy;
      float e0 = (dxy | (mz & (0 ^ ((l16>>1)&1)))) ? 0.f : __expf(s[im][jn][0]*scale);
      float e1 = (dxy | (mz & (0 ^ ((l16>>1)&1)))) ? 0.f : __expf(s[im][jn][1]*scale);
      float e2 = (dxy | (mz & (1 ^ ((l16>>1)&1)))) ? 0.f : __expf(s[im][jn][2]*scale);
      float e3 = (dxy | (mz & (1 ^ ((l16>>1)&1)))) ? 0.f : __expf(s[im][jn][3]*scale);
      sum4[jn] += (e0+e1)+(e2+e3);
      uint2 pk;
      pk.x = f2bf(e0) | (f2bf(e1)<<16);
      pk.y = f2bf(e2) | (f2bf(e3)<<16);
      *(uint2*)&P[(jn*16+l16)*72 + im*16 + q*4] = pk;   // row i, cols j..j+3
    }
  }
  #pragma unroll
  for (int jn = 0; jn < 4; ++jn){
    float sj = sum4[jn];
    sj += __shfl_xor(sj, 16);
    sj += __shfl_xor(sj, 32);
    sum4[jn] = 1.f / sj;
  }

  // O^T = V^T · P^T  (M=32 d, N=64 i, K=64 j)
  f32x4 o[2][4] = {};
  #pragma unroll
  for (int ks = 0; ks < 2; ++ks){
    short8 vf[2], pf[4];
    #pragma unroll
    for (int dt = 0; dt < 2; ++dt)
      vf[dt] = *(const short8*)&VT[(dt*16 + l16)*72 + ks*32 + q*8];
    #pragma unroll
    for (int it = 0; it < 4; ++it)
      pf[it] = *(const short8*)&P[(it*16 + l16)*72 + ks*32 + q*8];
    #pragma unroll
    for (int dt = 0; dt < 2; ++dt)
      #pragma unroll
      for (int it = 0; it < 4; ++it)
        o[dt][it] = __builtin_amdgcn_mfma_f32_16x16x32_bf16(vf[dt], pf[it], o[dt][it], 0, 0, 0);
  }

  // epilogue: O^T[d=dt*16+q*4+r][i=it*16+l16] * inv[it] -> aout[tok_v(i)]
  #pragma unroll
  for (int it = 0; it < 4; ++it){
    float inv = sum4[it];
    unsigned short* op = aout + (size_t)tok_v[it]*256 + head*32;
    #pragma unroll
    for (int dt = 0; dt < 2; ++dt){
      uint2 pk;
      pk.x = f2bf(o[dt][it][0]*inv) | (f2bf(o[dt][it][1]*inv) << 16);
      pk.y = f2bf(o[dt][it][2]*inv) | (f2bf(o[dt][it][3]*inv) << 16);
      *(uint2*)(op + dt*16 + q*4) = pk;
    }
  }
}

// ------------------------------- launch ---------------------------------------
extern "C" void kernel_launch(void* const* d_in, const int* in_sizes, int n_in,
                              void* d_out, int out_size, void* d_ws, size_t ws_size,
                              hipStream_t stream) {
  const float* x     = (const float*)d_in[0];  // [NT][256] fp32
  const float* w_qkv = (const float*)d_in[1];  // [256][768] fp32
  const float* w_out = (const float*)d_in[2];  // [256][256] fp32
  const float* b_out = (const float*)d_in[3];  // [256] fp32
  float* out = (float*)d_out;                  // [NT][256] fp32

  unsigned short* qkv   = (unsigned short*)d_ws;                 // NT*768 bf16
  unsigned short* xbf   = qkv   + (size_t)NT*768;                // NT*256 bf16 (aliases aout)
  unsigned short* aout  = xbf;                                   // reused after GEMM1
  unsigned short* wqkvT = xbf   + (size_t)NT*256;                // 768*256 bf16
  unsigned short* woutT = wqkvT + (size_t)768*256;               // 256*256 bf16
  // total ws use ≈ 227 MB

  xconv<<<dim3(NT*256/2048), dim3(256), 0, stream>>>(x, xbf);
  tpose<<<dim3((256*768 + 255)/256), dim3(256), 0, stream>>>(w_qkv, wqkvT, 256, 768);
  tpose<<<dim3((256*256 + 255)/256), dim3(256), 0, stream>>>(w_out, woutT, 256, 256);

  // 1D grid + in-kernel XCD-bijective swizzle: A-strip fetched once per XCD
  gemm_bt<false><<<dim3((768/128)*(NT/128)), dim3(512), 0, stream>>>(xbf, wqkvT, nullptr, qkv, NT, 768, 256);

  attn3d<<<dim3(13824/4), dim3(256), 0, stream>>>(qkv, aout);

  gemm_bt<true><<<dim3((256/128)*(NT/128)), dim3(512), 0, stream>>>(aout, woutT, b_out, out, NT, 256, 256);
}